// Round 7
// baseline (555.519 us; speedup 1.0000x reference)
//
#include <hip/hip_runtime.h>
#include <math.h>

#define N_NODES 50000
#define N_EDGES 800000
#define N_QE    100000
#define D       128

// ---- workspace layout (bytes) ----
static const size_t O_CNT = 0;                        // int[N]
static const size_t O_OFF = 256u * 1024;              // int[N+1]
static const size_t O_CUR = 512u * 1024;              // int[N]
static const size_t O_BS  = 768u * 1024;              // int[256] block sums
static const size_t O_SRC = 1024u * 1024;             // int[E] (3.2 MB)
static const size_t O_A   = 8u << 20;                 // float[N*D] 25.6 MB
static const size_t O_B   = O_A + 25600000u;          // float[N*D] 25.6 MB

// ---- CSR build ----
__global__ void k_count(const int* __restrict__ dst, int* __restrict__ cnt) {
    int e = blockIdx.x * 256 + threadIdx.x;
    if (e < N_EDGES) atomicAdd(&cnt[dst[e]], 1);
}

__global__ __launch_bounds__(256)
void k_scan1(const int* __restrict__ cnt, int* __restrict__ off,
             int* __restrict__ bsum) {
    __shared__ int sh[256];
    const int t = threadIdx.x;
    const int i = blockIdx.x * 256 + t;
    int v = (i < N_NODES) ? cnt[i] : 0;
    sh[t] = v;
    __syncthreads();
    #pragma unroll
    for (int o = 1; o < 256; o <<= 1) {
        int u = (t >= o) ? sh[t - o] : 0;
        __syncthreads();
        sh[t] += u;
        __syncthreads();
    }
    if (i < N_NODES) off[i] = sh[t] - v;
    if (t == 255) bsum[blockIdx.x] = sh[255];
}

__global__ __launch_bounds__(256)
void k_scan2(int* __restrict__ bsum, int nblk) {
    __shared__ int sh[256];
    const int t = threadIdx.x;
    int v = (t < nblk) ? bsum[t] : 0;
    sh[t] = v;
    __syncthreads();
    #pragma unroll
    for (int o = 1; o < 256; o <<= 1) {
        int u = (t >= o) ? sh[t - o] : 0;
        __syncthreads();
        sh[t] += u;
        __syncthreads();
    }
    if (t < nblk) bsum[t] = sh[t] - v;
}

__global__ __launch_bounds__(256)
void k_scan3(int* __restrict__ off, const int* __restrict__ bsum,
             int* __restrict__ cur) {
    const int i = blockIdx.x * 256 + threadIdx.x;
    if (i < N_NODES) {
        int o = off[i] + bsum[blockIdx.x];
        off[i] = o;
        cur[i] = o;
    }
    if (i == 0) off[N_NODES] = N_EDGES;
}

__global__ void k_scatter(const int* __restrict__ src, const int* __restrict__ dst,
                          int* __restrict__ cur, int* __restrict__ srcs) {
    int e = blockIdx.x * 256 + threadIdx.x;
    if (e < N_EDGES) {
        int p = atomicAdd(&cur[dst[e]], 1);
        srcs[p] = src[e];
    }
}

// ---- GEMM: Y[rows x 128] = X[rows x 128] @ W[128 x 128], fp32 ----
// 32-k chunked staging: LDS ~25.6 KB. In-place safe (X==Y).
__global__ __launch_bounds__(256)
void k_gemm(const float* __restrict__ X, const float* __restrict__ W,
            float* __restrict__ Y, int rows)
{
    __shared__ float xs[64][36];      // 32-k chunk of X, +4 pad
    __shared__ float ws[32 * 128];    // 32-k chunk of W
    const int tid = threadIdx.x;
    const int tx = tid & 31;
    const int ty = tid >> 5;
    const int row0 = blockIdx.x * 64;
    float acc[8][4] = {};

    for (int kc = 0; kc < 4; ++kc) {
        const int kb = kc * 32;
        __syncthreads();
        #pragma unroll
        for (int it = 0; it < 2; ++it) {
            int f = it * 256 + tid;
            int r = f >> 3, kq = f & 7;
            int gr = row0 + r; if (gr >= rows) gr = rows - 1;
            float4 v = *(const float4*)(X + (size_t)gr * D + kb + kq * 4);
            *(float4*)&xs[r][kq * 4] = v;
        }
        #pragma unroll
        for (int it = 0; it < 4; ++it) {
            int f = it * 256 + tid;
            int k = f >> 5, cq = f & 31;
            *(float4*)&ws[k * 128 + cq * 4] =
                *(const float4*)(W + (size_t)(kb + k) * D + cq * 4);
        }
        __syncthreads();

        #pragma unroll 2
        for (int k4 = 0; k4 < 32; k4 += 4) {
            float4 wv[4];
            #pragma unroll
            for (int kk = 0; kk < 4; ++kk)
                wv[kk] = *(const float4*)&ws[(k4 + kk) * 128 + tx * 4];
            #pragma unroll
            for (int i = 0; i < 8; ++i) {
                float4 xv = *(const float4*)&xs[ty * 8 + i][k4];
                float xk[4] = {xv.x, xv.y, xv.z, xv.w};
                #pragma unroll
                for (int kk = 0; kk < 4; ++kk) {
                    acc[i][0] = fmaf(xk[kk], wv[kk].x, acc[i][0]);
                    acc[i][1] = fmaf(xk[kk], wv[kk].y, acc[i][1]);
                    acc[i][2] = fmaf(xk[kk], wv[kk].z, acc[i][2]);
                    acc[i][3] = fmaf(xk[kk], wv[kk].w, acc[i][3]);
                }
            }
        }
    }

    #pragma unroll
    for (int i = 0; i < 8; ++i) {
        int gr = row0 + ty * 8 + i;
        if (gr < rows)
            *(float4*)(Y + (size_t)gr * D + tx * 4) =
                make_float4(acc[i][0], acc[i][1], acc[i][2], acc[i][3]);
    }
}

// ---- CSR aggregation (fp32): Hout[n] = sum Hin[src] + bias, opt relu ----
// 2 waves per node (each sums half the edge list), 2 nodes per block.
// Within a wave: lane=(half,q), 2 edges x 512B in flight, indices preloaded
// coalesced + shfl broadcast. LDS combine of the two wave partials.
template<bool RELU>
__global__ __launch_bounds__(256)
void k_agg(const float* __restrict__ Hin, const int* __restrict__ off,
           const int* __restrict__ srcs, const float* __restrict__ bias,
           float* __restrict__ Hout)
{
    __shared__ float4 red[4][32];
    const int tid  = threadIdx.x;
    const int lane = tid & 63;
    const int wid  = tid >> 6;          // 0..3
    const int slot = wid >> 1;          // node slot within block
    const int sub  = wid & 1;           // which half of the edge list
    const int n    = blockIdx.x * 2 + slot;
    const int half = lane >> 5;
    const int q    = lane & 31;
    const int j0 = off[n], j1 = off[n + 1];
    const int mid = j0 + ((j1 - j0 + 1) >> 1);
    const int jb = sub ? mid : j0;
    const int je = sub ? j1 : mid;

    float4 acc = make_float4(0.f, 0.f, 0.f, 0.f);
    int j = jb;
    while (j < je) {
        int cnt = je - j; if (cnt > 64) cnt = 64;
        int idx = (lane < cnt) ? srcs[j + lane] : 0;
        #pragma unroll 8
        for (int k = half; k < cnt; k += 2) {
            int s = __shfl(idx, k, 64);
            const float4 v = *(const float4*)(Hin + (size_t)s * D + q * 4);
            acc.x += v.x; acc.y += v.y; acc.z += v.z; acc.w += v.w;
        }
        j += cnt;
    }
    acc.x += __shfl_xor(acc.x, 32, 64);
    acc.y += __shfl_xor(acc.y, 32, 64);
    acc.z += __shfl_xor(acc.z, 32, 64);
    acc.w += __shfl_xor(acc.w, 32, 64);
    if (half == 0) red[wid][q] = acc;
    __syncthreads();
    if (sub == 0 && half == 0) {
        float4 a = red[wid][q];
        float4 b = red[wid + 1][q];
        const float4 bb = *(const float4*)(bias + q * 4);
        float4 o = make_float4(a.x + b.x + bb.x, a.y + b.y + bb.y,
                               a.z + b.z + bb.z, a.w + b.w + bb.w);
        if (RELU) {
            o.x = fmaxf(o.x, 0.f); o.y = fmaxf(o.y, 0.f);
            o.z = fmaxf(o.z, 0.f); o.w = fmaxf(o.w, 0.f);
        }
        *(float4*)(Hout + (size_t)n * D + q * 4) = o;
    }
}

// ---- fused link predictor ----
// Per block: 64 edges. z = emb[s]*emb[d] in LDS; two chained 128x128 GEMMs
// with DOUBLE-BUFFERED 32-k weight chunks (register prefetch overlaps the
// previous chunk's compute; one barrier per chunk); P3 dot + normalize +
// log_softmax epilogue.
__global__ __launch_bounds__(256)
void k_pred(const float* __restrict__ emb, const int* __restrict__ te,
            const float* __restrict__ P1, const float* __restrict__ pb1,
            const float* __restrict__ P2, const float* __restrict__ pb2,
            const float* __restrict__ P3, const float* __restrict__ pb3,
            float* __restrict__ out)
{
    __shared__ float xs[64][132];       // full 128-k activations, +4 pad
    __shared__ float ws[2][32 * 128];   // double-buffered 32-k weight chunks
    const int tid = threadIdx.x;
    const int tx = tid & 31;
    const int ty = tid >> 5;
    const int row0 = blockIdx.x * 64;

    // stage z0 = emb[s] * emb[d]
    #pragma unroll
    for (int it = 0; it < 8; ++it) {
        int slot = it * 256 + tid;          // 0..2047
        int r = slot >> 5, c4 = slot & 31;
        int e = row0 + r; if (e >= N_QE) e = N_QE - 1;
        int s = te[e * 2], d = te[e * 2 + 1];
        float4 a = *(const float4*)(emb + (size_t)s * D + c4 * 4);
        float4 b = *(const float4*)(emb + (size_t)d * D + c4 * 4);
        *(float4*)&xs[r][c4 * 4] =
            make_float4(a.x * b.x, a.y * b.y, a.z * b.z, a.w * b.w);
    }

    const int sk = (tid >> 5) & 31;         // not used; keep simple below
    (void)sk;
    float acc[8][4];
    float4 pf[4];
    const int pk = tid >> 5;                // unused helper removed
    (void)pk;

    #pragma unroll
    for (int layer = 0; layer < 2; ++layer) {
        const float* W = layer ? P2 : P1;
        const float* bb = layer ? pb2 : pb1;
        #pragma unroll
        for (int i = 0; i < 8; ++i)
            #pragma unroll
            for (int c = 0; c < 4; ++c) acc[i][c] = 0.f;

        // prefetch chunk 0 into registers
        #pragma unroll
        for (int it = 0; it < 4; ++it) {
            int f = it * 256 + tid;
            int k = f >> 5, cq = f & 31;
            pf[it] = *(const float4*)(W + (size_t)k * D + cq * 4);
        }

        int buf = 0;
        for (int kc = 0; kc < 4; ++kc) {
            // commit prefetched chunk to LDS
            #pragma unroll
            for (int it = 0; it < 4; ++it) {
                int f = it * 256 + tid;
                int k = f >> 5, cq = f & 31;
                *(float4*)&ws[buf][k * 128 + cq * 4] = pf[it];
            }
            // issue prefetch for next chunk (overlaps compute below)
            if (kc < 3) {
                const int kb2 = (kc + 1) * 32;
                #pragma unroll
                for (int it = 0; it < 4; ++it) {
                    int f = it * 256 + tid;
                    int k = f >> 5, cq = f & 31;
                    pf[it] = *(const float4*)(W + (size_t)(kb2 + k) * D + cq * 4);
                }
            }
            __syncthreads();

            const int kb = kc * 32;
            #pragma unroll 2
            for (int k4 = 0; k4 < 32; k4 += 4) {
                float4 wv[4];
                #pragma unroll
                for (int kk = 0; kk < 4; ++kk)
                    wv[kk] = *(const float4*)&ws[buf][(k4 + kk) * 128 + tx * 4];
                #pragma unroll
                for (int i = 0; i < 8; ++i) {
                    float4 xv = *(const float4*)&xs[ty * 8 + i][kb + k4];
                    float xk[4] = {xv.x, xv.y, xv.z, xv.w};
                    #pragma unroll
                    for (int kk = 0; kk < 4; ++kk) {
                        acc[i][0] = fmaf(xk[kk], wv[kk].x, acc[i][0]);
                        acc[i][1] = fmaf(xk[kk], wv[kk].y, acc[i][1]);
                        acc[i][2] = fmaf(xk[kk], wv[kk].z, acc[i][2]);
                        acc[i][3] = fmaf(xk[kk], wv[kk].w, acc[i][3]);
                    }
                }
            }
            buf ^= 1;
        }
        // bias + relu
        #pragma unroll
        for (int i = 0; i < 8; ++i) {
            acc[i][0] = fmaxf(acc[i][0] + bb[tx * 4 + 0], 0.f);
            acc[i][1] = fmaxf(acc[i][1] + bb[tx * 4 + 1], 0.f);
            acc[i][2] = fmaxf(acc[i][2] + bb[tx * 4 + 2], 0.f);
            acc[i][3] = fmaxf(acc[i][3] + bb[tx * 4 + 3], 0.f);
        }
        if (layer == 0) {
            __syncthreads();              // all xs (z0) reads done
            #pragma unroll
            for (int i = 0; i < 8; ++i)
                *(float4*)&xs[ty * 8 + i][tx * 4] =
                    make_float4(acc[i][0], acc[i][1], acc[i][2], acc[i][3]);
        }
    }

    // epilogue: v = z @ P3 + pb3 (2 cols), reduce over 32 lanes per half-wave
    float4 p3a = *(const float4*)(P3 + tx * 8);      // rows tx*4,tx*4+1
    float4 p3b = *(const float4*)(P3 + tx * 8 + 4);  // rows tx*4+2,tx*4+3
    const float q0 = pb3[0], q1 = pb3[1];
    #pragma unroll
    for (int i = 0; i < 8; ++i) {
        float p0 = acc[i][0] * p3a.x + acc[i][1] * p3a.z
                 + acc[i][2] * p3b.x + acc[i][3] * p3b.z;
        float p1 = acc[i][0] * p3a.y + acc[i][1] * p3a.w
                 + acc[i][2] * p3b.y + acc[i][3] * p3b.w;
        #pragma unroll
        for (int o = 1; o < 32; o <<= 1) {
            p0 += __shfl_xor(p0, o, 64);
            p1 += __shfl_xor(p1, o, 64);
        }
        if (tx == 0) {
            int gr = row0 + ty * 8 + i;
            if (gr < N_QE) {
                float v0 = p0 + q0, v1 = p1 + q1;
                float nrm = fmaxf(sqrtf(v0 * v0 + v1 * v1), 1e-12f);
                v0 /= nrm; v1 /= nrm;
                float m = fmaxf(v0, v1);
                float lse = m + logf(expf(v0 - m) + expf(v1 - m));
                out[gr * 2]     = v0 - lse;
                out[gr * 2 + 1] = v1 - lse;
            }
        }
    }
}

extern "C" void kernel_launch(void* const* d_in, const int* in_sizes, int n_in,
                              void* d_out, int out_size, void* d_ws, size_t ws_size,
                              hipStream_t stream)
{
    (void)in_sizes; (void)n_in; (void)out_size; (void)ws_size;
    const float* x   = (const float*)d_in[0];
    const int*   adj = (const int*)d_in[1];
    const int*   te  = (const int*)d_in[2];
    const float* W1  = (const float*)d_in[3];
    const float* b1  = (const float*)d_in[4];
    const float* W2  = (const float*)d_in[5];
    const float* b2  = (const float*)d_in[6];
    const float* W3  = (const float*)d_in[7];
    const float* b3  = (const float*)d_in[8];
    const float* P1  = (const float*)d_in[9];
    const float* pb1 = (const float*)d_in[10];
    const float* P2  = (const float*)d_in[11];
    const float* pb2 = (const float*)d_in[12];
    const float* P3  = (const float*)d_in[13];
    const float* pb3 = (const float*)d_in[14];
    float* out = (float*)d_out;

    char* ws = (char*)d_ws;
    int* cnt  = (int*)(ws + O_CNT);
    int* off  = (int*)(ws + O_OFF);
    int* cur  = (int*)(ws + O_CUR);
    int* bsum = (int*)(ws + O_BS);
    int* srcs = (int*)(ws + O_SRC);
    float* A  = (float*)(ws + O_A);
    float* B  = (float*)(ws + O_B);

    const int* esrc = adj;
    const int* edst = adj + N_EDGES;

    const int SBLK = (N_NODES + 255) / 256;   // 196

    // CSR build (dst-sorted src list), reused by all 3 layers
    hipMemsetAsync(cnt, 0, N_NODES * sizeof(int), stream);
    k_count<<<N_EDGES / 256, 256, 0, stream>>>(edst, cnt);
    k_scan1<<<SBLK, 256, 0, stream>>>(cnt, off, bsum);
    k_scan2<<<1, 256, 0, stream>>>(bsum, SBLK);
    k_scan3<<<SBLK, 256, 0, stream>>>(off, bsum, cur);
    k_scatter<<<N_EDGES / 256, 256, 0, stream>>>(esrc, edst, cur, srcs);

    const int gN = (N_NODES + 63) / 64;   // 782
    const int gQ = (N_QE + 63) / 64;      // 1563

    // GCN trunk (all fp32)
    k_gemm<<<gN, 256, 0, stream>>>(x, W1, A, N_NODES);
    k_agg<true><<<N_NODES / 2, 256, 0, stream>>>(A, off, srcs, b1, B);
    k_gemm<<<gN, 256, 0, stream>>>(B, W2, B, N_NODES);
    k_agg<true><<<N_NODES / 2, 256, 0, stream>>>(B, off, srcs, b2, A);
    k_gemm<<<gN, 256, 0, stream>>>(A, W3, A, N_NODES);
    k_agg<false><<<N_NODES / 2, 256, 0, stream>>>(A, off, srcs, b3, B); // B = emb

    // fused link predictor
    k_pred<<<gQ, 256, 0, stream>>>(B, te, P1, pb1, P2, pb2, P3, pb3, out);
}

// Round 8
// 538.282 us; speedup vs baseline: 1.0320x; 1.0320x over previous
//
#include <hip/hip_runtime.h>
#include <math.h>

#define N_NODES 50000
#define N_EDGES 800000
#define N_QE    100000
#define D       128

// ---- workspace layout (bytes) ----
static const size_t O_CNT = 0;                        // int[N]
static const size_t O_OFF = 256u * 1024;              // int[N+1]
static const size_t O_CUR = 512u * 1024;              // int[N]
static const size_t O_BS  = 768u * 1024;              // int[256] block sums
static const size_t O_SRC = 1024u * 1024;             // int[E] (3.2 MB)
static const size_t O_A   = 8u << 20;                 // float[N*D] 25.6 MB
static const size_t O_B   = O_A + 25600000u;          // float[N*D] 25.6 MB

// ---- CSR build ----
__global__ void k_count(const int* __restrict__ dst, int* __restrict__ cnt) {
    int e = blockIdx.x * 256 + threadIdx.x;
    if (e < N_EDGES) atomicAdd(&cnt[dst[e]], 1);
}

__global__ __launch_bounds__(256)
void k_scan1(const int* __restrict__ cnt, int* __restrict__ off,
             int* __restrict__ bsum) {
    __shared__ int sh[256];
    const int t = threadIdx.x;
    const int i = blockIdx.x * 256 + t;
    int v = (i < N_NODES) ? cnt[i] : 0;
    sh[t] = v;
    __syncthreads();
    #pragma unroll
    for (int o = 1; o < 256; o <<= 1) {
        int u = (t >= o) ? sh[t - o] : 0;
        __syncthreads();
        sh[t] += u;
        __syncthreads();
    }
    if (i < N_NODES) off[i] = sh[t] - v;
    if (t == 255) bsum[blockIdx.x] = sh[255];
}

__global__ __launch_bounds__(256)
void k_scan2(int* __restrict__ bsum, int nblk) {
    __shared__ int sh[256];
    const int t = threadIdx.x;
    int v = (t < nblk) ? bsum[t] : 0;
    sh[t] = v;
    __syncthreads();
    #pragma unroll
    for (int o = 1; o < 256; o <<= 1) {
        int u = (t >= o) ? sh[t - o] : 0;
        __syncthreads();
        sh[t] += u;
        __syncthreads();
    }
    if (t < nblk) bsum[t] = sh[t] - v;
}

__global__ __launch_bounds__(256)
void k_scan3(int* __restrict__ off, const int* __restrict__ bsum,
             int* __restrict__ cur) {
    const int i = blockIdx.x * 256 + threadIdx.x;
    if (i < N_NODES) {
        int o = off[i] + bsum[blockIdx.x];
        off[i] = o;
        cur[i] = o;
    }
    if (i == 0) off[N_NODES] = N_EDGES;
}

__global__ void k_scatter(const int* __restrict__ src, const int* __restrict__ dst,
                          int* __restrict__ cur, int* __restrict__ srcs) {
    int e = blockIdx.x * 256 + threadIdx.x;
    if (e < N_EDGES) {
        int p = atomicAdd(&cur[dst[e]], 1);
        srcs[p] = src[e];
    }
}

// ---- GEMM: Y[rows x 128] = X[rows x 128] @ W[128 x 128], fp32 ----
// 32-k chunked staging: LDS ~25.6 KB. In-place safe (X==Y).
__global__ __launch_bounds__(256)
void k_gemm(const float* __restrict__ X, const float* __restrict__ W,
            float* __restrict__ Y, int rows)
{
    __shared__ float xs[64][36];      // 32-k chunk of X, +4 pad
    __shared__ float ws[32 * 128];    // 32-k chunk of W
    const int tid = threadIdx.x;
    const int tx = tid & 31;
    const int ty = tid >> 5;
    const int row0 = blockIdx.x * 64;
    float acc[8][4] = {};

    for (int kc = 0; kc < 4; ++kc) {
        const int kb = kc * 32;
        __syncthreads();
        #pragma unroll
        for (int it = 0; it < 2; ++it) {
            int f = it * 256 + tid;
            int r = f >> 3, kq = f & 7;
            int gr = row0 + r; if (gr >= rows) gr = rows - 1;
            float4 v = *(const float4*)(X + (size_t)gr * D + kb + kq * 4);
            *(float4*)&xs[r][kq * 4] = v;
        }
        #pragma unroll
        for (int it = 0; it < 4; ++it) {
            int f = it * 256 + tid;
            int k = f >> 5, cq = f & 31;
            *(float4*)&ws[k * 128 + cq * 4] =
                *(const float4*)(W + (size_t)(kb + k) * D + cq * 4);
        }
        __syncthreads();

        #pragma unroll 2
        for (int k4 = 0; k4 < 32; k4 += 4) {
            float4 wv[4];
            #pragma unroll
            for (int kk = 0; kk < 4; ++kk)
                wv[kk] = *(const float4*)&ws[(k4 + kk) * 128 + tx * 4];
            #pragma unroll
            for (int i = 0; i < 8; ++i) {
                float4 xv = *(const float4*)&xs[ty * 8 + i][k4];
                float xk[4] = {xv.x, xv.y, xv.z, xv.w};
                #pragma unroll
                for (int kk = 0; kk < 4; ++kk) {
                    acc[i][0] = fmaf(xk[kk], wv[kk].x, acc[i][0]);
                    acc[i][1] = fmaf(xk[kk], wv[kk].y, acc[i][1]);
                    acc[i][2] = fmaf(xk[kk], wv[kk].z, acc[i][2]);
                    acc[i][3] = fmaf(xk[kk], wv[kk].w, acc[i][3]);
                }
            }
        }
    }

    #pragma unroll
    for (int i = 0; i < 8; ++i) {
        int gr = row0 + ty * 8 + i;
        if (gr < rows)
            *(float4*)(Y + (size_t)gr * D + tx * 4) =
                make_float4(acc[i][0], acc[i][1], acc[i][2], acc[i][3]);
    }
}

// ---- CSR aggregation (fp32): Hout[n] = sum Hin[src] + bias, opt relu ----
// 2 waves per node (each sums half the edge list), 2 nodes per block.
template<bool RELU>
__global__ __launch_bounds__(256)
void k_agg(const float* __restrict__ Hin, const int* __restrict__ off,
           const int* __restrict__ srcs, const float* __restrict__ bias,
           float* __restrict__ Hout)
{
    __shared__ float4 red[4][32];
    const int tid  = threadIdx.x;
    const int lane = tid & 63;
    const int wid  = tid >> 6;          // 0..3
    const int slot = wid >> 1;          // node slot within block
    const int sub  = wid & 1;           // which half of the edge list
    const int n    = blockIdx.x * 2 + slot;
    const int half = lane >> 5;
    const int q    = lane & 31;
    const int j0 = off[n], j1 = off[n + 1];
    const int mid = j0 + ((j1 - j0 + 1) >> 1);
    const int jb = sub ? mid : j0;
    const int je = sub ? j1 : mid;

    float4 acc = make_float4(0.f, 0.f, 0.f, 0.f);
    int j = jb;
    while (j < je) {
        int cnt = je - j; if (cnt > 64) cnt = 64;
        int idx = (lane < cnt) ? srcs[j + lane] : 0;
        #pragma unroll 8
        for (int k = half; k < cnt; k += 2) {
            int s = __shfl(idx, k, 64);
            const float4 v = *(const float4*)(Hin + (size_t)s * D + q * 4);
            acc.x += v.x; acc.y += v.y; acc.z += v.z; acc.w += v.w;
        }
        j += cnt;
    }
    acc.x += __shfl_xor(acc.x, 32, 64);
    acc.y += __shfl_xor(acc.y, 32, 64);
    acc.z += __shfl_xor(acc.z, 32, 64);
    acc.w += __shfl_xor(acc.w, 32, 64);
    if (half == 0) red[wid][q] = acc;
    __syncthreads();
    if (sub == 0 && half == 0) {
        float4 a = red[wid][q];
        float4 b = red[wid + 1][q];
        const float4 bb = *(const float4*)(bias + q * 4);
        float4 o = make_float4(a.x + b.x + bb.x, a.y + b.y + bb.y,
                               a.z + b.z + bb.z, a.w + b.w + bb.w);
        if (RELU) {
            o.x = fmaxf(o.x, 0.f); o.y = fmaxf(o.y, 0.f);
            o.z = fmaxf(o.z, 0.f); o.w = fmaxf(o.w, 0.f);
        }
        *(float4*)(Hout + (size_t)n * D + q * 4) = o;
    }
}

// ---- fused link predictor, 512 threads / 64 edges per block ----
// 8 waves/block x 2 blocks/CU = 16 waves/CU (2x the 256-thread variant) to
// hide the z0-gather head and per-chunk staging latency. Each thread owns
// 4 rows x 4 cols. Single-buffered 64-k weight chunks (fewest instructions).
__global__ __launch_bounds__(512)
void k_pred(const float* __restrict__ emb, const int* __restrict__ te,
            const float* __restrict__ P1, const float* __restrict__ pb1,
            const float* __restrict__ P2, const float* __restrict__ pb2,
            const float* __restrict__ P3, const float* __restrict__ pb3,
            float* __restrict__ out)
{
    __shared__ float xs[64][132];     // full 128-k activations, +4 pad
    __shared__ float ws[64 * 128];    // one 64-k weight chunk
    const int tid = threadIdx.x;      // 0..511
    const int tx = tid & 31;          // cols tx*4 .. +3
    const int ty = tid >> 5;          // 0..15, rows ty*4 .. +3
    const int row0 = blockIdx.x * 64;

    // stage z0 = emb[s] * emb[d]  (2048 float4 slots / 512 threads)
    #pragma unroll
    for (int it = 0; it < 4; ++it) {
        int slot = it * 512 + tid;          // 0..2047
        int r = slot >> 5, c4 = slot & 31;
        int e = row0 + r; if (e >= N_QE) e = N_QE - 1;
        int s = te[e * 2], d = te[e * 2 + 1];
        float4 a = *(const float4*)(emb + (size_t)s * D + c4 * 4);
        float4 b = *(const float4*)(emb + (size_t)d * D + c4 * 4);
        *(float4*)&xs[r][c4 * 4] =
            make_float4(a.x * b.x, a.y * b.y, a.z * b.z, a.w * b.w);
    }

    float acc[4][4];

    #pragma unroll
    for (int layer = 0; layer < 2; ++layer) {
        const float* W = layer ? P2 : P1;
        const float* bb = layer ? pb2 : pb1;
        #pragma unroll
        for (int i = 0; i < 4; ++i)
            #pragma unroll
            for (int c = 0; c < 4; ++c) acc[i][c] = 0.f;

        for (int kc = 0; kc < 2; ++kc) {
            const int kb = kc * 64;
            __syncthreads();              // ws free of previous readers / xs ready
            #pragma unroll
            for (int it = 0; it < 4; ++it) {
                int f = it * 512 + tid;   // 0..2047
                int k = f >> 5, cq = f & 31;
                *(float4*)&ws[k * 128 + cq * 4] =
                    *(const float4*)(W + (size_t)(kb + k) * D + cq * 4);
            }
            __syncthreads();

            #pragma unroll 2
            for (int k4 = 0; k4 < 64; k4 += 4) {
                float4 wv[4];
                #pragma unroll
                for (int kk = 0; kk < 4; ++kk)
                    wv[kk] = *(const float4*)&ws[(k4 + kk) * 128 + tx * 4];
                #pragma unroll
                for (int i = 0; i < 4; ++i) {
                    float4 xv = *(const float4*)&xs[ty * 4 + i][kb + k4];
                    float xk[4] = {xv.x, xv.y, xv.z, xv.w};
                    #pragma unroll
                    for (int kk = 0; kk < 4; ++kk) {
                        acc[i][0] = fmaf(xk[kk], wv[kk].x, acc[i][0]);
                        acc[i][1] = fmaf(xk[kk], wv[kk].y, acc[i][1]);
                        acc[i][2] = fmaf(xk[kk], wv[kk].z, acc[i][2]);
                        acc[i][3] = fmaf(xk[kk], wv[kk].w, acc[i][3]);
                    }
                }
            }
        }
        // bias + relu
        #pragma unroll
        for (int i = 0; i < 4; ++i) {
            acc[i][0] = fmaxf(acc[i][0] + bb[tx * 4 + 0], 0.f);
            acc[i][1] = fmaxf(acc[i][1] + bb[tx * 4 + 1], 0.f);
            acc[i][2] = fmaxf(acc[i][2] + bb[tx * 4 + 2], 0.f);
            acc[i][3] = fmaxf(acc[i][3] + bb[tx * 4 + 3], 0.f);
        }
        if (layer == 0) {
            __syncthreads();              // all xs (z0) reads done
            #pragma unroll
            for (int i = 0; i < 4; ++i)
                *(float4*)&xs[ty * 4 + i][tx * 4] =
                    make_float4(acc[i][0], acc[i][1], acc[i][2], acc[i][3]);
        }
    }

    // epilogue: v = z @ P3 + pb3 (2 cols), reduce over the 32 tx lanes
    float4 p3a = *(const float4*)(P3 + tx * 8);      // rows tx*4,tx*4+1
    float4 p3b = *(const float4*)(P3 + tx * 8 + 4);  // rows tx*4+2,tx*4+3
    const float q0 = pb3[0], q1 = pb3[1];
    #pragma unroll
    for (int i = 0; i < 4; ++i) {
        float p0 = acc[i][0] * p3a.x + acc[i][1] * p3a.z
                 + acc[i][2] * p3b.x + acc[i][3] * p3b.z;
        float p1 = acc[i][0] * p3a.y + acc[i][1] * p3a.w
                 + acc[i][2] * p3b.y + acc[i][3] * p3b.w;
        #pragma unroll
        for (int o = 1; o < 32; o <<= 1) {     // stays within 32-lane half (ty const)
            p0 += __shfl_xor(p0, o, 64);
            p1 += __shfl_xor(p1, o, 64);
        }
        if (tx == 0) {
            int gr = row0 + ty * 4 + i;
            if (gr < N_QE) {
                float v0 = p0 + q0, v1 = p1 + q1;
                float nrm = fmaxf(sqrtf(v0 * v0 + v1 * v1), 1e-12f);
                v0 /= nrm; v1 /= nrm;
                float m = fmaxf(v0, v1);
                float lse = m + logf(expf(v0 - m) + expf(v1 - m));
                out[gr * 2]     = v0 - lse;
                out[gr * 2 + 1] = v1 - lse;
            }
        }
    }
}

extern "C" void kernel_launch(void* const* d_in, const int* in_sizes, int n_in,
                              void* d_out, int out_size, void* d_ws, size_t ws_size,
                              hipStream_t stream)
{
    (void)in_sizes; (void)n_in; (void)out_size; (void)ws_size;
    const float* x   = (const float*)d_in[0];
    const int*   adj = (const int*)d_in[1];
    const int*   te  = (const int*)d_in[2];
    const float* W1  = (const float*)d_in[3];
    const float* b1  = (const float*)d_in[4];
    const float* W2  = (const float*)d_in[5];
    const float* b2  = (const float*)d_in[6];
    const float* W3  = (const float*)d_in[7];
    const float* b3  = (const float*)d_in[8];
    const float* P1  = (const float*)d_in[9];
    const float* pb1 = (const float*)d_in[10];
    const float* P2  = (const float*)d_in[11];
    const float* pb2 = (const float*)d_in[12];
    const float* P3  = (const float*)d_in[13];
    const float* pb3 = (const float*)d_in[14];
    float* out = (float*)d_out;

    char* ws = (char*)d_ws;
    int* cnt  = (int*)(ws + O_CNT);
    int* off  = (int*)(ws + O_OFF);
    int* cur  = (int*)(ws + O_CUR);
    int* bsum = (int*)(ws + O_BS);
    int* srcs = (int*)(ws + O_SRC);
    float* A  = (float*)(ws + O_A);
    float* B  = (float*)(ws + O_B);

    const int* esrc = adj;
    const int* edst = adj + N_EDGES;

    const int SBLK = (N_NODES + 255) / 256;   // 196

    // CSR build (dst-sorted src list), reused by all 3 layers
    hipMemsetAsync(cnt, 0, N_NODES * sizeof(int), stream);
    k_count<<<N_EDGES / 256, 256, 0, stream>>>(edst, cnt);
    k_scan1<<<SBLK, 256, 0, stream>>>(cnt, off, bsum);
    k_scan2<<<1, 256, 0, stream>>>(bsum, SBLK);
    k_scan3<<<SBLK, 256, 0, stream>>>(off, bsum, cur);
    k_scatter<<<N_EDGES / 256, 256, 0, stream>>>(esrc, edst, cur, srcs);

    const int gN = (N_NODES + 63) / 64;   // 782
    const int gQ = (N_QE + 63) / 64;      // 1563

    // GCN trunk (all fp32)
    k_gemm<<<gN, 256, 0, stream>>>(x, W1, A, N_NODES);
    k_agg<true><<<N_NODES / 2, 256, 0, stream>>>(A, off, srcs, b1, B);
    k_gemm<<<gN, 256, 0, stream>>>(B, W2, B, N_NODES);
    k_agg<true><<<N_NODES / 2, 256, 0, stream>>>(B, off, srcs, b2, A);
    k_gemm<<<gN, 256, 0, stream>>>(A, W3, A, N_NODES);
    k_agg<false><<<N_NODES / 2, 256, 0, stream>>>(A, off, srcs, b3, B); // B = emb

    // fused link predictor (512 threads / 64 edges per block)
    k_pred<<<gQ, 512, 0, stream>>>(B, te, P1, pb1, P2, pb2, P3, pb3, out);
}

// Round 9
// 536.493 us; speedup vs baseline: 1.0355x; 1.0033x over previous
//
#include <hip/hip_runtime.h>
#include <math.h>

#define N_NODES 50000
#define N_EDGES 800000
#define N_QE    100000
#define D       128

// ---- workspace layout (bytes) ----
static const size_t O_CNT = 0;                        // int[N]
static const size_t O_OFF = 256u * 1024;              // int[N+1]
static const size_t O_CUR = 512u * 1024;              // int[N]
static const size_t O_BS  = 768u * 1024;              // int[256] block sums
static const size_t O_SRC = 1024u * 1024;             // int[E] (3.2 MB)
static const size_t O_A   = 8u << 20;                 // float[N*D] 25.6 MB
static const size_t O_B   = O_A + 25600000u;          // float[N*D] 25.6 MB

// ---- CSR build ----
__global__ void k_count(const int* __restrict__ dst, int* __restrict__ cnt) {
    int e = blockIdx.x * 256 + threadIdx.x;
    if (e < N_EDGES) atomicAdd(&cnt[dst[e]], 1);
}

__global__ __launch_bounds__(256)
void k_scan1(const int* __restrict__ cnt, int* __restrict__ off,
             int* __restrict__ bsum) {
    __shared__ int sh[256];
    const int t = threadIdx.x;
    const int i = blockIdx.x * 256 + t;
    int v = (i < N_NODES) ? cnt[i] : 0;
    sh[t] = v;
    __syncthreads();
    #pragma unroll
    for (int o = 1; o < 256; o <<= 1) {
        int u = (t >= o) ? sh[t - o] : 0;
        __syncthreads();
        sh[t] += u;
        __syncthreads();
    }
    if (i < N_NODES) off[i] = sh[t] - v;
    if (t == 255) bsum[blockIdx.x] = sh[255];
}

__global__ __launch_bounds__(256)
void k_scan2(int* __restrict__ bsum, int nblk) {
    __shared__ int sh[256];
    const int t = threadIdx.x;
    int v = (t < nblk) ? bsum[t] : 0;
    sh[t] = v;
    __syncthreads();
    #pragma unroll
    for (int o = 1; o < 256; o <<= 1) {
        int u = (t >= o) ? sh[t - o] : 0;
        __syncthreads();
        sh[t] += u;
        __syncthreads();
    }
    if (t < nblk) bsum[t] = sh[t] - v;
}

__global__ __launch_bounds__(256)
void k_scan3(int* __restrict__ off, const int* __restrict__ bsum,
             int* __restrict__ cur) {
    const int i = blockIdx.x * 256 + threadIdx.x;
    if (i < N_NODES) {
        int o = off[i] + bsum[blockIdx.x];
        off[i] = o;
        cur[i] = o;
    }
    if (i == 0) off[N_NODES] = N_EDGES;
}

__global__ void k_scatter(const int* __restrict__ src, const int* __restrict__ dst,
                          int* __restrict__ cur, int* __restrict__ srcs) {
    int e = blockIdx.x * 256 + threadIdx.x;
    if (e < N_EDGES) {
        int p = atomicAdd(&cur[dst[e]], 1);
        srcs[p] = src[e];
    }
}

// ---- GEMM: Y[rows x 128] = X[rows x 128] @ W[128 x 128], fp32 ----
// 512 threads / 64-row tile (8 waves/block -> 2x waves/CU under the observed
// ~2-block/CU scheduler cap). 32-k chunks, LDS ~25.6 KB. In-place safe.
__global__ __launch_bounds__(512)
void k_gemm(const float* __restrict__ X, const float* __restrict__ W,
            float* __restrict__ Y, int rows)
{
    __shared__ float xs[64][36];      // 32-k chunk of X, +4 pad
    __shared__ float ws[32 * 128];    // 32-k chunk of W
    const int tid = threadIdx.x;      // 0..511
    const int tx = tid & 31;          // cols tx*4..+3
    const int ty = tid >> 5;          // 0..15, rows ty*4..+3
    const int row0 = blockIdx.x * 64;
    float acc[4][4] = {};

    for (int kc = 0; kc < 4; ++kc) {
        const int kb = kc * 32;
        __syncthreads();
        {   // stage X tile: 512 float4 slots, 1 per thread
            int r = tid >> 3, kq = tid & 7;
            int gr = row0 + r; if (gr >= rows) gr = rows - 1;
            float4 v = *(const float4*)(X + (size_t)gr * D + kb + kq * 4);
            *(float4*)&xs[r][kq * 4] = v;
        }
        #pragma unroll
        for (int it = 0; it < 2; ++it) {   // stage W: 1024 float4 / 512 threads
            int f = it * 512 + tid;
            int k = f >> 5, cq = f & 31;
            *(float4*)&ws[k * 128 + cq * 4] =
                *(const float4*)(W + (size_t)(kb + k) * D + cq * 4);
        }
        __syncthreads();

        #pragma unroll 2
        for (int k4 = 0; k4 < 32; k4 += 4) {
            float4 wv[4];
            #pragma unroll
            for (int kk = 0; kk < 4; ++kk)
                wv[kk] = *(const float4*)&ws[(k4 + kk) * 128 + tx * 4];
            #pragma unroll
            for (int i = 0; i < 4; ++i) {
                float4 xv = *(const float4*)&xs[ty * 4 + i][k4];
                float xk[4] = {xv.x, xv.y, xv.z, xv.w};
                #pragma unroll
                for (int kk = 0; kk < 4; ++kk) {
                    acc[i][0] = fmaf(xk[kk], wv[kk].x, acc[i][0]);
                    acc[i][1] = fmaf(xk[kk], wv[kk].y, acc[i][1]);
                    acc[i][2] = fmaf(xk[kk], wv[kk].z, acc[i][2]);
                    acc[i][3] = fmaf(xk[kk], wv[kk].w, acc[i][3]);
                }
            }
        }
    }

    #pragma unroll
    for (int i = 0; i < 4; ++i) {
        int gr = row0 + ty * 4 + i;
        if (gr < rows)
            *(float4*)(Y + (size_t)gr * D + tx * 4) =
                make_float4(acc[i][0], acc[i][1], acc[i][2], acc[i][3]);
    }
}

// ---- CSR aggregation (fp32): Hout[n] = sum Hin[src] + bias, opt relu ----
// 2 waves per node (each sums half the edge list), 2 nodes per block.
template<bool RELU>
__global__ __launch_bounds__(256)
void k_agg(const float* __restrict__ Hin, const int* __restrict__ off,
           const int* __restrict__ srcs, const float* __restrict__ bias,
           float* __restrict__ Hout)
{
    __shared__ float4 red[4][32];
    const int tid  = threadIdx.x;
    const int lane = tid & 63;
    const int wid  = tid >> 6;          // 0..3
    const int slot = wid >> 1;          // node slot within block
    const int sub  = wid & 1;           // which half of the edge list
    const int n    = blockIdx.x * 2 + slot;
    const int half = lane >> 5;
    const int q    = lane & 31;
    const int j0 = off[n], j1 = off[n + 1];
    const int mid = j0 + ((j1 - j0 + 1) >> 1);
    const int jb = sub ? mid : j0;
    const int je = sub ? j1 : mid;

    float4 acc = make_float4(0.f, 0.f, 0.f, 0.f);
    int j = jb;
    while (j < je) {
        int cnt = je - j; if (cnt > 64) cnt = 64;
        int idx = (lane < cnt) ? srcs[j + lane] : 0;
        #pragma unroll 8
        for (int k = half; k < cnt; k += 2) {
            int s = __shfl(idx, k, 64);
            const float4 v = *(const float4*)(Hin + (size_t)s * D + q * 4);
            acc.x += v.x; acc.y += v.y; acc.z += v.z; acc.w += v.w;
        }
        j += cnt;
    }
    acc.x += __shfl_xor(acc.x, 32, 64);
    acc.y += __shfl_xor(acc.y, 32, 64);
    acc.z += __shfl_xor(acc.z, 32, 64);
    acc.w += __shfl_xor(acc.w, 32, 64);
    if (half == 0) red[wid][q] = acc;
    __syncthreads();
    if (sub == 0 && half == 0) {
        float4 a = red[wid][q];
        float4 b = red[wid + 1][q];
        const float4 bb = *(const float4*)(bias + q * 4);
        float4 o = make_float4(a.x + b.x + bb.x, a.y + b.y + bb.y,
                               a.z + b.z + bb.z, a.w + b.w + bb.w);
        if (RELU) {
            o.x = fmaxf(o.x, 0.f); o.y = fmaxf(o.y, 0.f);
            o.z = fmaxf(o.z, 0.f); o.w = fmaxf(o.w, 0.f);
        }
        *(float4*)(Hout + (size_t)n * D + q * 4) = o;
    }
}

// ---- fused link predictor, 512 threads / 64 edges per block ----
// 32-k weight chunks -> LDS 50.2 KB (< 53.3 KB 3-block threshold).
// Each thread owns 4 rows x 4 cols.
__global__ __launch_bounds__(512)
void k_pred(const float* __restrict__ emb, const int* __restrict__ te,
            const float* __restrict__ P1, const float* __restrict__ pb1,
            const float* __restrict__ P2, const float* __restrict__ pb2,
            const float* __restrict__ P3, const float* __restrict__ pb3,
            float* __restrict__ out)
{
    __shared__ float xs[64][132];     // full 128-k activations, +4 pad (33.8 KB)
    __shared__ float ws[32 * 128];    // one 32-k weight chunk (16.4 KB)
    const int tid = threadIdx.x;      // 0..511
    const int tx = tid & 31;          // cols tx*4 .. +3
    const int ty = tid >> 5;          // 0..15, rows ty*4 .. +3
    const int row0 = blockIdx.x * 64;

    // stage z0 = emb[s] * emb[d]  (2048 float4 slots / 512 threads)
    #pragma unroll
    for (int it = 0; it < 4; ++it) {
        int slot = it * 512 + tid;          // 0..2047
        int r = slot >> 5, c4 = slot & 31;
        int e = row0 + r; if (e >= N_QE) e = N_QE - 1;
        int s = te[e * 2], d = te[e * 2 + 1];
        float4 a = *(const float4*)(emb + (size_t)s * D + c4 * 4);
        float4 b = *(const float4*)(emb + (size_t)d * D + c4 * 4);
        *(float4*)&xs[r][c4 * 4] =
            make_float4(a.x * b.x, a.y * b.y, a.z * b.z, a.w * b.w);
    }

    float acc[4][4];

    #pragma unroll
    for (int layer = 0; layer < 2; ++layer) {
        const float* W = layer ? P2 : P1;
        const float* bb = layer ? pb2 : pb1;
        #pragma unroll
        for (int i = 0; i < 4; ++i)
            #pragma unroll
            for (int c = 0; c < 4; ++c) acc[i][c] = 0.f;

        for (int kc = 0; kc < 4; ++kc) {
            const int kb = kc * 32;
            __syncthreads();              // ws free of previous readers / xs ready
            #pragma unroll
            for (int it = 0; it < 2; ++it) {
                int f = it * 512 + tid;   // 0..1023
                int k = f >> 5, cq = f & 31;
                *(float4*)&ws[k * 128 + cq * 4] =
                    *(const float4*)(W + (size_t)(kb + k) * D + cq * 4);
            }
            __syncthreads();

            #pragma unroll 2
            for (int k4 = 0; k4 < 32; k4 += 4) {
                float4 wv[4];
                #pragma unroll
                for (int kk = 0; kk < 4; ++kk)
                    wv[kk] = *(const float4*)&ws[(k4 + kk) * 128 + tx * 4];
                #pragma unroll
                for (int i = 0; i < 4; ++i) {
                    float4 xv = *(const float4*)&xs[ty * 4 + i][kb + k4];
                    float xk[4] = {xv.x, xv.y, xv.z, xv.w};
                    #pragma unroll
                    for (int kk = 0; kk < 4; ++kk) {
                        acc[i][0] = fmaf(xk[kk], wv[kk].x, acc[i][0]);
                        acc[i][1] = fmaf(xk[kk], wv[kk].y, acc[i][1]);
                        acc[i][2] = fmaf(xk[kk], wv[kk].z, acc[i][2]);
                        acc[i][3] = fmaf(xk[kk], wv[kk].w, acc[i][3]);
                    }
                }
            }
        }
        // bias + relu
        #pragma unroll
        for (int i = 0; i < 4; ++i) {
            acc[i][0] = fmaxf(acc[i][0] + bb[tx * 4 + 0], 0.f);
            acc[i][1] = fmaxf(acc[i][1] + bb[tx * 4 + 1], 0.f);
            acc[i][2] = fmaxf(acc[i][2] + bb[tx * 4 + 2], 0.f);
            acc[i][3] = fmaxf(acc[i][3] + bb[tx * 4 + 3], 0.f);
        }
        if (layer == 0) {
            __syncthreads();              // all xs (z0) reads done
            #pragma unroll
            for (int i = 0; i < 4; ++i)
                *(float4*)&xs[ty * 4 + i][tx * 4] =
                    make_float4(acc[i][0], acc[i][1], acc[i][2], acc[i][3]);
        }
    }

    // epilogue: v = z @ P3 + pb3 (2 cols), reduce over the 32 tx lanes
    float4 p3a = *(const float4*)(P3 + tx * 8);      // rows tx*4,tx*4+1
    float4 p3b = *(const float4*)(P3 + tx * 8 + 4);  // rows tx*4+2,tx*4+3
    const float q0 = pb3[0], q1 = pb3[1];
    #pragma unroll
    for (int i = 0; i < 4; ++i) {
        float p0 = acc[i][0] * p3a.x + acc[i][1] * p3a.z
                 + acc[i][2] * p3b.x + acc[i][3] * p3b.z;
        float p1 = acc[i][0] * p3a.y + acc[i][1] * p3a.w
                 + acc[i][2] * p3b.y + acc[i][3] * p3b.w;
        #pragma unroll
        for (int o = 1; o < 32; o <<= 1) {     // stays within 32-lane half
            p0 += __shfl_xor(p0, o, 64);
            p1 += __shfl_xor(p1, o, 64);
        }
        if (tx == 0) {
            int gr = row0 + ty * 4 + i;
            if (gr < N_QE) {
                float v0 = p0 + q0, v1 = p1 + q1;
                float nrm = fmaxf(sqrtf(v0 * v0 + v1 * v1), 1e-12f);
                v0 /= nrm; v1 /= nrm;
                float m = fmaxf(v0, v1);
                float lse = m + logf(expf(v0 - m) + expf(v1 - m));
                out[gr * 2]     = v0 - lse;
                out[gr * 2 + 1] = v1 - lse;
            }
        }
    }
}

extern "C" void kernel_launch(void* const* d_in, const int* in_sizes, int n_in,
                              void* d_out, int out_size, void* d_ws, size_t ws_size,
                              hipStream_t stream)
{
    (void)in_sizes; (void)n_in; (void)out_size; (void)ws_size;
    const float* x   = (const float*)d_in[0];
    const int*   adj = (const int*)d_in[1];
    const int*   te  = (const int*)d_in[2];
    const float* W1  = (const float*)d_in[3];
    const float* b1  = (const float*)d_in[4];
    const float* W2  = (const float*)d_in[5];
    const float* b2  = (const float*)d_in[6];
    const float* W3  = (const float*)d_in[7];
    const float* b3  = (const float*)d_in[8];
    const float* P1  = (const float*)d_in[9];
    const float* pb1 = (const float*)d_in[10];
    const float* P2  = (const float*)d_in[11];
    const float* pb2 = (const float*)d_in[12];
    const float* P3  = (const float*)d_in[13];
    const float* pb3 = (const float*)d_in[14];
    float* out = (float*)d_out;

    char* ws = (char*)d_ws;
    int* cnt  = (int*)(ws + O_CNT);
    int* off  = (int*)(ws + O_OFF);
    int* cur  = (int*)(ws + O_CUR);
    int* bsum = (int*)(ws + O_BS);
    int* srcs = (int*)(ws + O_SRC);
    float* A  = (float*)(ws + O_A);
    float* B  = (float*)(ws + O_B);

    const int* esrc = adj;
    const int* edst = adj + N_EDGES;

    const int SBLK = (N_NODES + 255) / 256;   // 196

    // CSR build (dst-sorted src list), reused by all 3 layers
    hipMemsetAsync(cnt, 0, N_NODES * sizeof(int), stream);
    k_count<<<N_EDGES / 256, 256, 0, stream>>>(edst, cnt);
    k_scan1<<<SBLK, 256, 0, stream>>>(cnt, off, bsum);
    k_scan2<<<1, 256, 0, stream>>>(bsum, SBLK);
    k_scan3<<<SBLK, 256, 0, stream>>>(off, bsum, cur);
    k_scatter<<<N_EDGES / 256, 256, 0, stream>>>(esrc, edst, cur, srcs);

    const int gN = (N_NODES + 63) / 64;   // 782
    const int gQ = (N_QE + 63) / 64;      // 1563

    // GCN trunk (all fp32, 512-thread gemms)
    k_gemm<<<gN, 512, 0, stream>>>(x, W1, A, N_NODES);
    k_agg<true><<<N_NODES / 2, 256, 0, stream>>>(A, off, srcs, b1, B);
    k_gemm<<<gN, 512, 0, stream>>>(B, W2, B, N_NODES);
    k_agg<true><<<N_NODES / 2, 256, 0, stream>>>(B, off, srcs, b2, A);
    k_gemm<<<gN, 512, 0, stream>>>(A, W3, A, N_NODES);
    k_agg<false><<<N_NODES / 2, 256, 0, stream>>>(A, off, srcs, b3, B); // B = emb

    // fused link predictor (512 threads, 32-k chunks, LDS 50.2 KB)
    k_pred<<<gQ, 512, 0, stream>>>(B, te, P1, pb1, P2, pb2, P3, pb3, out);
}